// Round 11
// baseline (152.587 us; speedup 1.0000x reference)
//
#include <hip/hip_runtime.h>
#include <hip/hip_bf16.h>

typedef __attribute__((ext_vector_type(4))) float floatx4;

#define C_DIM 256
#define INV_T 14.285714285714286f
// (1/T) * log2(e) : logits scaled to base-2 so exp2f -> v_exp_f32 directly.
#define K2_SCALE 20.60992915f

// pack 4 fp32 -> 4 OCP fp8 e4m3 bytes in one dword (ascending order)
__device__ __forceinline__ unsigned int pack4fp8(float a, float b, float c, float d) {
    int w = __builtin_amdgcn_cvt_pk_fp8_f32(a, b, 0, false);
    w = __builtin_amdgcn_cvt_pk_fp8_f32(c, d, w, true);
    return (unsigned int)w;
}

// DPP add within a 16-lane row (VALU pipe; R10-proven)
template <int CTRL>
__device__ __forceinline__ float dppadd(float x) {
    int y = __builtin_amdgcn_update_dpp(0, __builtin_bit_cast(int, x),
                                        CTRL, 0xf, 0xf, true);
    return x + __builtin_bit_cast(float, y);
}
__device__ __forceinline__ float row16_sum(float x) {
    x = dppadd<0xB1>(x);    // quad_perm xor1
    x = dppadd<0x4E>(x);    // quad_perm xor2
    x = dppadd<0x124>(x);   // row_ror:4
    x = dppadd<0x128>(x);   // row_ror:8
    return x;
}

// ---------------------------------------------------------------------------
// Kernel 1: fused prep. 128 blocks x 64 rows. Per 16-row group:
//  - threads 0..15 compute the row labels straight from coords/seg (no
//    cross-kernel dependency), write lab[] for rows < N, LDS-hist them;
//  - 4 waves L2-normalize 4 rows each -> gn (fp32, row-major) and LDS nrm;
//  - writer phase emits the group's fragment-tiled fp8 blob (16 B/thread,
//    R10-verified index algebra) and accumulates class-sum vectors
//    Sloc[5][256] in LDS (thread t owns dim t -> no races).
// End: 1280 global f32 atomics into S, 8 int atomics into hist.
// S/hist/acc zeroed by a capture-safe hipMemsetAsync before launch.
// ---------------------------------------------------------------------------
__global__ __launch_bounds__(256) void
norm_kernel(const float* __restrict__ f,
            unsigned char* __restrict__ g2,
            float* __restrict__ gn,
            const int* __restrict__ seg,
            const int* __restrict__ coords,
            const int* __restrict__ crw,
            const int* __restrict__ crh,
            const int* __restrict__ crd,
            int* __restrict__ lab,
            float* __restrict__ S,        // [5][256]
            int* __restrict__ hist,       // [8]
            int N, int H, int W, int D) {
    __shared__ float nrm[16][264];
    __shared__ float Sloc[5][256];
    __shared__ int lbl[16];
    __shared__ int histloc[8];

    const int tid = threadIdx.x;
    const int bid = blockIdx.x;
    const int lane = tid & 63;
    const int wave = tid >> 6;
    const int rbase = bid * 64;

    if (tid < 8) histloc[tid] = 0;
#pragma unroll
    for (int c = 0; c < 5; ++c) Sloc[c][tid] = 0.0f;
    __syncthreads();

    for (int g = 0; g < 4; ++g) {
        const int grow0 = rbase + g * 16;
        if (tid < 16) {
            const int row = grow0 + tid;
            const int p = row & (N - 1);
            int c0 = coords[3 * p + 0];
            int c1 = coords[3 * p + 1];
            int c2 = coords[3 * p + 2];
            int i0 = (c0 * H) / crw[0];
            int i1 = (c1 * W) / crh[0];
            int i2 = (c2 * D) / crd[0];
            const int c = seg[(i0 * W + i1) * D + i2];
            lbl[tid] = c;
            if (row < N) {
                lab[row] = c;
                atomicAdd(&histloc[c], 1);
            }
        }
        const int rl = wave * 4;
#pragma unroll
        for (int q = 0; q < 4; ++q) {
            const int row = grow0 + rl + q;
            const float4 v = ((const float4*)(f + (size_t)row * C_DIM))[lane];
            float ss = v.x * v.x + v.y * v.y + v.z * v.z + v.w * v.w;
#pragma unroll
            for (int off = 32; off; off >>= 1) ss += __shfl_xor(ss, off, 64);
            const float inv = 1.0f / sqrtf(ss);
            const float4 o = float4{v.x * inv, v.y * inv, v.z * inv, v.w * inv};
            *(float4*)&nrm[rl + q][lane * 4] = o;
            *(float4*)(gn + (size_t)row * C_DIM + lane * 4) = o;
        }
        __syncthreads();

        // fragment-tiled fp8 writer: thread t -> blob bytes [16t, 16t+16)
        const int k0 = (tid >> 5) * 32 + ((tid >> 3) & 3) * 8;
        const float* ra = &nrm[(2 * tid) & 15][k0];
        const float* rb = &nrm[(2 * tid + 1) & 15][k0];
        uint4 o;
        o.x = pack4fp8(ra[0], ra[1], ra[2], ra[3]);
        o.y = pack4fp8(ra[4], ra[5], ra[6], ra[7]);
        o.z = pack4fp8(rb[0], rb[1], rb[2], rb[3]);
        o.w = pack4fp8(rb[4], rb[5], rb[6], rb[7]);
        *(uint4*)(g2 + (size_t)(bid * 4 + g) * 4096 + (size_t)tid * 16) = o;

        // class-sum accumulation: thread t owns dim t
#pragma unroll
        for (int rr = 0; rr < 16; ++rr)
            Sloc[lbl[rr]][tid] += nrm[rr][tid];
        __syncthreads();
    }

#pragma unroll
    for (int c = 0; c < 5; ++c)
        unsafeAtomicAdd(&S[c * 256 + tid], Sloc[c][tid]);
    if (tid < 8 && histloc[tid] > 0) atomicAdd(&hist[tid], histloc[tid]);
}

// ---------------------------------------------------------------------------
// Kernel 2: chunked-persistent symmetric Gram kernel (se-only epilogue).
// 512 blocks; block b runs 4-5 contiguous triangular tiles: A restaged only
// on tm change, diagonal tiles alias B to A. One-shot width-16
// global_load_lds staging, one barrier, barrier-free fp8 MFMA K-loop from
// LDS. Epilogue tracks ONLY se = sum exp((sim-1)/T) (diag masked): DPP
// row-sum (A-side) / 2 shuffles (B-side) -> 2 KB LDS -> exactly-once
// coalesced stores into part[slot][M] (A -> slot tn rows tm; B -> slot tm
// rows tn). nu/cnt are reconstructed in finalize from S/hist.
// ---------------------------------------------------------------------------
__global__ __launch_bounds__(256, 2) void
gram_kernel(const unsigned char* __restrict__ G2,
            float* __restrict__ part,
            int M, int nt) {
    __shared__ unsigned char Abuf[32768];
    __shared__ unsigned char Bbuf[32768];
    __shared__ float red[2][2][128];

    const int tid = threadIdx.x;
    const int bid = blockIdx.x;
    const int lane = tid & 63;
    const int wave = tid >> 6;
    const int waveM = wave >> 1;
    const int waveN = wave & 1;
    const int cc = lane & 15;
    const int cq = lane >> 4;

    const int start = bid * 4 + (bid < 32 ? bid : 32);
    const int len = 4 + (bid < 32 ? 1 : 0);
    int tmPrev = -1;

    for (int s = 0; s < len; ++s) {
        const int idx = start + s;
        float fnt = (float)nt;
        float disc = (2.0f * fnt + 1.0f) * (2.0f * fnt + 1.0f) - 8.0f * (float)idx;
        int tm = (int)((2.0f * fnt + 1.0f - sqrtf(disc)) * 0.5f);
        if (tm < 0) tm = 0;
        if (tm > nt - 1) tm = nt - 1;
        while (tm > 0 && idx < tm * nt - tm * (tm - 1) / 2) --tm;
        while (idx >= (tm + 1) * nt - (tm + 1) * tm / 2) ++tm;
        const int tn = tm + (idx - (tm * nt - tm * (tm - 1) / 2));

        const int rowA0 = tm * 128;
        const int rowB0 = tn * 128;
        const bool diagTile = (tm == tn);

        if (tm != tmPrev) {
            const unsigned char* gA = G2 + (size_t)tm * 32768;
#pragma unroll
            for (int i = 0; i < 8; ++i) {
                const int u = i * 256 + tid;
                __builtin_amdgcn_global_load_lds(
                    (const __attribute__((address_space(1))) void*)(gA + (size_t)u * 16),
                    (__attribute__((address_space(3))) void*)(&Abuf[(u & ~63) * 16]),
                    16, 0, 0);
            }
            tmPrev = tm;
        }
        if (!diagTile) {
            const unsigned char* gB = G2 + (size_t)tn * 32768;
#pragma unroll
            for (int i = 0; i < 8; ++i) {
                const int u = i * 256 + tid;
                __builtin_amdgcn_global_load_lds(
                    (const __attribute__((address_space(1))) void*)(gB + (size_t)u * 16),
                    (__attribute__((address_space(3))) void*)(&Bbuf[(u & ~63) * 16]),
                    16, 0, 0);
            }
        }
        __syncthreads();

        const unsigned char* A = Abuf;
        const unsigned char* B = diagTile ? Abuf : Bbuf;

        floatx4 acc[4][4];
#pragma unroll
        for (int mi = 0; mi < 4; ++mi)
#pragma unroll
            for (int ni = 0; ni < 4; ++ni)
                acc[mi][ni] = floatx4{-1.0f, -1.0f, -1.0f, -1.0f};  // folds (sim-1)

#pragma unroll
        for (int ks = 0; ks < 8; ++ks) {  // K = 8 * 32 = 256
            long af[4], bf[4];
#pragma unroll
            for (int mi = 0; mi < 4; ++mi)
                af[mi] = *(const long*)&A[(size_t)((waveM * 4 + mi) * 8 + ks) * 512 + lane * 8];
#pragma unroll
            for (int ni = 0; ni < 4; ++ni)
                bf[ni] = *(const long*)&B[(size_t)((waveN * 4 + ni) * 8 + ks) * 512 + lane * 8];
#pragma unroll
            for (int mi = 0; mi < 4; ++mi)
#pragma unroll
                for (int ni = 0; ni < 4; ++ni)
                    acc[mi][ni] = __builtin_amdgcn_mfma_f32_16x16x32_fp8_fp8(
                        af[mi], bf[ni], acc[mi][ni], 0, 0, 0);
        }

        // ---- se-only epilogue ----
        float bse[4] = {};
#pragma unroll
        for (int mi = 0; mi < 4; ++mi) {
#pragma unroll
            for (int r = 0; r < 4; ++r) {
                const int lrow = waveM * 64 + mi * 16 + cq * 4 + r;
                const int grow = rowA0 + lrow;
                float se = 0.0f;
#pragma unroll
                for (int ni = 0; ni < 4; ++ni) {
                    const int gcol = rowB0 + waveN * 64 + ni * 16 + cc;
                    const float e = exp2f(acc[mi][ni][r] * K2_SCALE);
                    const float ev = (gcol != grow) ? e : 0.0f;
                    se += ev;
                    bse[ni] += ev;
                }
                se = row16_sum(se);
                if (cc == 0) red[0][waveN][lrow] = se;
            }
        }
        if (!diagTile) {
#pragma unroll
            for (int ni = 0; ni < 4; ++ni) {
                float se = bse[ni];
                se += __shfl_xor(se, 16, 64);
                se += __shfl_xor(se, 32, 64);
                if (cq == 0) red[1][waveM][waveN * 64 + ni * 16 + cc] = se;
            }
        }
        __syncthreads();

        if (tid < 128)
            part[(size_t)tn * M + rowA0 + tid] = red[0][0][tid] + red[0][1][tid];
        if (!diagTile && tid >= 128)
            part[(size_t)tm * M + rowB0 + (tid - 128)] =
                red[1][0][tid - 128] + red[1][1][tid - 128];
        __syncthreads();
    }
}

// ---------------------------------------------------------------------------
// Kernel 3: finalize. 32 blocks x 256 rows.
//  A: load S (5x256) + hist into LDS; per-row: lab, se = sum of 64 part
//     slots (coalesced).
//  B: wave-per-row dot(gn_row, S[lab]) via float4 FMA + DPP row-sum.
//  C: term = (1/T)*((dot-1)/cnt - 1) - log(se); block reduce; acc/done
//     handshake; last block writes the loss.
// ---------------------------------------------------------------------------
__global__ __launch_bounds__(256) void
finalize_kernel(const float* __restrict__ part,
                const float* __restrict__ gn,
                const float* __restrict__ S,
                const int* __restrict__ hist,
                const int* __restrict__ lab,
                float* __restrict__ acc_done,
                float* __restrict__ out,
                int M, int N, int nslots, int nblk) {
    __shared__ float Sl[5][256];
    __shared__ float seL[256];
    __shared__ int labL[256];
    __shared__ float dot4[256][4];
    __shared__ float sred[256];

    const int tid = threadIdx.x;
    const int lane = tid & 63;
    const int wave = tid >> 6;
    const int r0 = blockIdx.x * 256;
    const int ntps = M / N;

#pragma unroll
    for (int c = 0; c < 5; ++c) Sl[c][tid] = S[c * 256 + tid];

    float se = 0.0f;
    for (int s = 0; s < nslots; ++s) se += part[(size_t)s * M + r0 + tid];
    seL[tid] = se;
    labL[tid] = lab[(r0 + tid) & (N - 1)];
    __syncthreads();

    // wave-per-row dot products
    for (int j = 0; j < 64; ++j) {
        const int lr = wave * 64 + j;
        const int row = r0 + lr;
        const int c = labL[lr];
        const float4 x = ((const float4*)(gn + (size_t)row * C_DIM))[lane];
        const float4 sv = *(const float4*)&Sl[c][lane * 4];
        float p = x.x * sv.x + x.y * sv.y + x.z * sv.z + x.w * sv.w;
        p = row16_sum(p);
        if ((lane & 15) == 0) dot4[lr][lane >> 4] = p;
    }
    __syncthreads();

    const float dot = dot4[tid][0] + dot4[tid][1] + dot4[tid][2] + dot4[tid][3];
    const float cnt = (float)(ntps * hist[labL[tid]] - 1);
    const float term = INV_T * ((dot - 1.0f) / cnt - 1.0f) - logf(seL[tid]);

    sred[tid] = term;
    __syncthreads();
    for (int k = 128; k; k >>= 1) {
        if (tid < k) sred[tid] += sred[tid + k];
        __syncthreads();
    }
    if (tid == 0) {
        atomicAdd(&acc_done[0], sred[0]);
        __threadfence();
        int old = atomicAdd((int*)&acc_done[1], 1);
        if (old == nblk - 1) {
            float total = atomicAdd(&acc_done[0], 0.0f);  // atomic read
            out[0] = -total / (float)M;
        }
    }
}

extern "C" void kernel_launch(void* const* d_in, const int* in_sizes, int n_in,
                              void* d_out, int out_size, void* d_ws, size_t ws_size,
                              hipStream_t stream) {
    const float* features = (const float*)d_in[0];
    const int* labels_seg = (const int*)d_in[1];
    const int* labels_coords = (const int*)d_in[2];
    const int* crw = (const int*)d_in[3];
    const int* crh = (const int*)d_in[4];
    const int* crd = (const int*)d_in[5];
    float* out = (float*)d_out;

    const int N = in_sizes[2] / 3;          // 4096 patches
    const int M = in_sizes[0] / C_DIM;      // 8192 rows
    const int H = 128, W = 128, D = 128;
    const int nt = M / 128;                 // 64 row-blocks

    // workspace layout
    char* ws = (char*)d_ws;
    unsigned char* g2 = (unsigned char*)ws;                  // 2 MB fp8 tiled
    char* p1 = ws + (size_t)M * C_DIM;
    float* gn = (float*)p1;                                  // 8 MB fp32 normalized
    char* p2 = p1 + (size_t)M * C_DIM * 4;
    int* lab = (int*)p2;                                     // N ints
    char* p3 = p2 + (size_t)N * 4;
    float* part = (float*)p3;                                // nt*M f32 (2 MB)
    char* p4 = p3 + (size_t)nt * M * 4;
    float* S = (float*)p4;                                   // 5*256 f32
    int* hist = (int*)(p4 + 5 * 256 * 4);                    // 8 ints
    float* acc_done = (float*)(p4 + 5 * 256 * 4 + 8 * 4);    // {acc, done}

    // zero S + hist + acc/done (capture-safe stream memset node)
    hipMemsetAsync(p4, 0, 5 * 256 * 4 + 8 * 4 + 8, stream);

    norm_kernel<<<M / 64, 256, 0, stream>>>(features, g2, gn, labels_seg,
                                            labels_coords, crw, crh, crd, lab,
                                            S, hist, N, H, W, D);

    gram_kernel<<<512, 256, 0, stream>>>(g2, part, M, nt);

    const int fblk = M / 256;               // 32
    finalize_kernel<<<fblk, 256, 0, stream>>>(part, gn, S, hist, lab, acc_done,
                                              out, M, N, nt, fblk);
}

// Round 12
// 151.520 us; speedup vs baseline: 1.0070x; 1.0070x over previous
//
#include <hip/hip_runtime.h>
#include <hip/hip_bf16.h>

typedef __attribute__((ext_vector_type(4))) float floatx4;

#define C_DIM 256
#define INV_T 14.285714285714286f
// (1/T) * log2(e) : logits scaled to base-2 so exp2f -> v_exp_f32 directly.
#define K2_SCALE 20.60992915f

// pack 4 fp32 -> 4 OCP fp8 e4m3 bytes in one dword (ascending order)
__device__ __forceinline__ unsigned int pack4fp8(float a, float b, float c, float d) {
    int w = __builtin_amdgcn_cvt_pk_fp8_f32(a, b, 0, false);
    w = __builtin_amdgcn_cvt_pk_fp8_f32(c, d, w, true);
    return (unsigned int)w;
}

// DPP add within a 16-lane row (VALU pipe; R10-proven)
template <int CTRL>
__device__ __forceinline__ float dppadd(float x) {
    int y = __builtin_amdgcn_update_dpp(0, __builtin_bit_cast(int, x),
                                        CTRL, 0xf, 0xf, true);
    return x + __builtin_bit_cast(float, y);
}
__device__ __forceinline__ float row16_sum(float x) {
    x = dppadd<0xB1>(x);    // quad_perm xor1
    x = dppadd<0x4E>(x);    // quad_perm xor2
    x = dppadd<0x124>(x);   // row_ror:4
    x = dppadd<0x128>(x);   // row_ror:8
    return x;
}

// ---------------------------------------------------------------------------
// Kernel 1: fused prep (NO memsets anywhere — everything exactly-once).
// 128 blocks x 64 rows. Per 16-row group: labels from coords/seg, normalize
// 4 rows/wave -> LDS, fragment-tiled fp8 writer (16 B/thread), class-sum
// accumulation Sloc[5][256] (thread t owns dim t). End: slot writes
// Spart[bid][5][256], histpart[bid][8]; gid 0 zeroes the finalize handshake
// (stream order guarantees it lands before finalize runs).
// ---------------------------------------------------------------------------
__global__ __launch_bounds__(256) void
norm_kernel(const float* __restrict__ f,
            unsigned char* __restrict__ g2,
            const int* __restrict__ seg,
            const int* __restrict__ coords,
            const int* __restrict__ crw,
            const int* __restrict__ crh,
            const int* __restrict__ crd,
            int* __restrict__ lab,
            float* __restrict__ Spart,    // [128][5][256]
            int* __restrict__ histpart,   // [128][8]
            float* __restrict__ acc_done,
            int N, int H, int W, int D) {
    __shared__ float nrm[16][264];
    __shared__ float Sloc[5][256];
    __shared__ int lbl[16];
    __shared__ int histloc[8];

    const int tid = threadIdx.x;
    const int bid = blockIdx.x;
    const int lane = tid & 63;
    const int wave = tid >> 6;
    const int rbase = bid * 64;

    if (bid == 0 && tid == 0) {
        acc_done[0] = 0.0f;
        ((int*)acc_done)[1] = 0;
    }
    if (tid < 8) histloc[tid] = 0;
#pragma unroll
    for (int c = 0; c < 5; ++c) Sloc[c][tid] = 0.0f;
    __syncthreads();

    for (int g = 0; g < 4; ++g) {
        const int grow0 = rbase + g * 16;
        if (tid < 16) {
            const int row = grow0 + tid;
            const int p = row & (N - 1);
            int c0 = coords[3 * p + 0];
            int c1 = coords[3 * p + 1];
            int c2 = coords[3 * p + 2];
            int i0 = (c0 * H) / crw[0];
            int i1 = (c1 * W) / crh[0];
            int i2 = (c2 * D) / crd[0];
            const int c = seg[(i0 * W + i1) * D + i2];
            lbl[tid] = c;
            if (row < N) {
                lab[row] = c;
                atomicAdd(&histloc[c], 1);
            }
        }
        const int rl = wave * 4;
#pragma unroll
        for (int q = 0; q < 4; ++q) {
            const int row = grow0 + rl + q;
            const float4 v = ((const float4*)(f + (size_t)row * C_DIM))[lane];
            float ss = v.x * v.x + v.y * v.y + v.z * v.z + v.w * v.w;
#pragma unroll
            for (int off = 32; off; off >>= 1) ss += __shfl_xor(ss, off, 64);
            const float inv = 1.0f / sqrtf(ss);
            *(float4*)&nrm[rl + q][lane * 4] =
                float4{v.x * inv, v.y * inv, v.z * inv, v.w * inv};
        }
        __syncthreads();

        // fragment-tiled fp8 writer: thread t -> blob bytes [16t, 16t+16)
        const int k0 = (tid >> 5) * 32 + ((tid >> 3) & 3) * 8;
        const float* ra = &nrm[(2 * tid) & 15][k0];
        const float* rb = &nrm[(2 * tid + 1) & 15][k0];
        uint4 o;
        o.x = pack4fp8(ra[0], ra[1], ra[2], ra[3]);
        o.y = pack4fp8(ra[4], ra[5], ra[6], ra[7]);
        o.z = pack4fp8(rb[0], rb[1], rb[2], rb[3]);
        o.w = pack4fp8(rb[4], rb[5], rb[6], rb[7]);
        *(uint4*)(g2 + (size_t)(bid * 4 + g) * 4096 + (size_t)tid * 16) = o;

        // class-sum accumulation: thread t owns dim t
#pragma unroll
        for (int rr = 0; rr < 16; ++rr)
            Sloc[lbl[rr]][tid] += nrm[rr][tid];
        __syncthreads();
    }

#pragma unroll
    for (int c = 0; c < 5; ++c)
        Spart[(size_t)bid * 1280 + c * 256 + tid] = Sloc[c][tid];
    if (tid < 8) histpart[bid * 8 + tid] = histloc[tid];
}

// ---------------------------------------------------------------------------
// Kernel 2: chunked-persistent symmetric Gram kernel (se-only epilogue),
// unchanged from R11 (verified absmax 0.0). 512 blocks; block b runs 4-5
// contiguous triangular tiles (A restaged only on tm change; diagonal tiles
// alias B to A). One-shot width-16 global_load_lds staging, one barrier,
// barrier-free fp8 MFMA K-loop from LDS. Epilogue: se only, DPP row-sum ->
// 1 KB LDS -> exactly-once stores into part[slot][M].
// ---------------------------------------------------------------------------
__global__ __launch_bounds__(256, 2) void
gram_kernel(const unsigned char* __restrict__ G2,
            float* __restrict__ part,
            int M, int nt) {
    __shared__ unsigned char Abuf[32768];
    __shared__ unsigned char Bbuf[32768];
    __shared__ float red[2][2][128];

    const int tid = threadIdx.x;
    const int bid = blockIdx.x;
    const int lane = tid & 63;
    const int wave = tid >> 6;
    const int waveM = wave >> 1;
    const int waveN = wave & 1;
    const int cc = lane & 15;
    const int cq = lane >> 4;

    const int start = bid * 4 + (bid < 32 ? bid : 32);
    const int len = 4 + (bid < 32 ? 1 : 0);
    int tmPrev = -1;

    for (int s = 0; s < len; ++s) {
        const int idx = start + s;
        float fnt = (float)nt;
        float disc = (2.0f * fnt + 1.0f) * (2.0f * fnt + 1.0f) - 8.0f * (float)idx;
        int tm = (int)((2.0f * fnt + 1.0f - sqrtf(disc)) * 0.5f);
        if (tm < 0) tm = 0;
        if (tm > nt - 1) tm = nt - 1;
        while (tm > 0 && idx < tm * nt - tm * (tm - 1) / 2) --tm;
        while (idx >= (tm + 1) * nt - (tm + 1) * tm / 2) ++tm;
        const int tn = tm + (idx - (tm * nt - tm * (tm - 1) / 2));

        const int rowA0 = tm * 128;
        const int rowB0 = tn * 128;
        const bool diagTile = (tm == tn);

        if (tm != tmPrev) {
            const unsigned char* gA = G2 + (size_t)tm * 32768;
#pragma unroll
            for (int i = 0; i < 8; ++i) {
                const int u = i * 256 + tid;
                __builtin_amdgcn_global_load_lds(
                    (const __attribute__((address_space(1))) void*)(gA + (size_t)u * 16),
                    (__attribute__((address_space(3))) void*)(&Abuf[(u & ~63) * 16]),
                    16, 0, 0);
            }
            tmPrev = tm;
        }
        if (!diagTile) {
            const unsigned char* gB = G2 + (size_t)tn * 32768;
#pragma unroll
            for (int i = 0; i < 8; ++i) {
                const int u = i * 256 + tid;
                __builtin_amdgcn_global_load_lds(
                    (const __attribute__((address_space(1))) void*)(gB + (size_t)u * 16),
                    (__attribute__((address_space(3))) void*)(&Bbuf[(u & ~63) * 16]),
                    16, 0, 0);
            }
        }
        __syncthreads();

        const unsigned char* A = Abuf;
        const unsigned char* B = diagTile ? Abuf : Bbuf;

        floatx4 acc[4][4];
#pragma unroll
        for (int mi = 0; mi < 4; ++mi)
#pragma unroll
            for (int ni = 0; ni < 4; ++ni)
                acc[mi][ni] = floatx4{-1.0f, -1.0f, -1.0f, -1.0f};  // folds (sim-1)

#pragma unroll
        for (int ks = 0; ks < 8; ++ks) {  // K = 8 * 32 = 256
            long af[4], bf[4];
#pragma unroll
            for (int mi = 0; mi < 4; ++mi)
                af[mi] = *(const long*)&A[(size_t)((waveM * 4 + mi) * 8 + ks) * 512 + lane * 8];
#pragma unroll
            for (int ni = 0; ni < 4; ++ni)
                bf[ni] = *(const long*)&B[(size_t)((waveN * 4 + ni) * 8 + ks) * 512 + lane * 8];
#pragma unroll
            for (int mi = 0; mi < 4; ++mi)
#pragma unroll
                for (int ni = 0; ni < 4; ++ni)
                    acc[mi][ni] = __builtin_amdgcn_mfma_f32_16x16x32_fp8_fp8(
                        af[mi], bf[ni], acc[mi][ni], 0, 0, 0);
        }

        // ---- se-only epilogue ----
        float bse[4] = {};
#pragma unroll
        for (int mi = 0; mi < 4; ++mi) {
#pragma unroll
            for (int r = 0; r < 4; ++r) {
                const int lrow = waveM * 64 + mi * 16 + cq * 4 + r;
                const int grow = rowA0 + lrow;
                float se = 0.0f;
#pragma unroll
                for (int ni = 0; ni < 4; ++ni) {
                    const int gcol = rowB0 + waveN * 64 + ni * 16 + cc;
                    const float e = exp2f(acc[mi][ni][r] * K2_SCALE);
                    const float ev = (gcol != grow) ? e : 0.0f;
                    se += ev;
                    bse[ni] += ev;
                }
                se = row16_sum(se);
                if (cc == 0) red[0][waveN][lrow] = se;
            }
        }
        if (!diagTile) {
#pragma unroll
            for (int ni = 0; ni < 4; ++ni) {
                float se = bse[ni];
                se += __shfl_xor(se, 16, 64);
                se += __shfl_xor(se, 32, 64);
                if (cq == 0) red[1][waveM][waveN * 64 + ni * 16 + cc] = se;
            }
        }
        __syncthreads();

        if (tid < 128)
            part[(size_t)tn * M + rowA0 + tid] = red[0][0][tid] + red[0][1][tid];
        if (!diagTile && tid >= 128)
            part[(size_t)tm * M + rowB0 + (tid - 128)] =
                red[1][0][tid - 128] + red[1][1][tid - 128];
        __syncthreads();
    }
}

// ---------------------------------------------------------------------------
// Kernel 3: finalize via the class-aggregate identity:
//   sum_i term_i = INV_T*( sum_c (|S_c|^2 - M_c)/cnt_c - M ) - sum_i log(se_i)
// (M_c = ntps*hist_c rows of class c, cnt_c = M_c - 1; per-row dots never
// materialized). 32 blocks x 256 rows: se = sum of 64 slots (coalesced),
// add -sum log(se). Block 0 additionally reduces Spart/histpart and adds the
// closed-form class term. acc/done handshake; last block writes the loss.
// ---------------------------------------------------------------------------
__global__ __launch_bounds__(256) void
finalize_kernel(const float* __restrict__ part,
                const float* __restrict__ Spart,
                const int* __restrict__ histpart,
                float* __restrict__ acc_done,
                float* __restrict__ out,
                int M, int N, int nslots, int nblk) {
    __shared__ float sred[256];
    __shared__ float Sl[5][256];
    __shared__ int hred[8];

    const int tid = threadIdx.x;
    const int r0 = blockIdx.x * 256;
    const int ntps = M / N;

    float se = 0.0f;
    for (int s = 0; s < nslots; ++s) se += part[(size_t)s * M + r0 + tid];
    float partial = -logf(se);

    sred[tid] = partial;
    __syncthreads();
    for (int k = 128; k; k >>= 1) {
        if (tid < k) sred[tid] += sred[tid + k];
        __syncthreads();
    }
    float blocksum = sred[0];

    if (blockIdx.x == 0) {
        // reduce class sums: Sl[c][d] = sum over 128 norm-blocks
#pragma unroll
        for (int c = 0; c < 5; ++c) {
            float acc = 0.0f;
            for (int b = 0; b < 128; ++b)
                acc += Spart[(size_t)b * 1280 + c * 256 + tid];
            Sl[c][tid] = acc;
        }
        if (tid < 8) {
            int h = 0;
            for (int b = 0; b < 128; ++b) h += histpart[b * 8 + tid];
            hred[tid] = h;
        }
        __syncthreads();

        // p = sum_c Sl[c][tid]^2 / cnt_c  (division distributed per class)
        float p = 0.0f;
#pragma unroll
        for (int c = 0; c < 5; ++c) {
            const float cnt = (float)(ntps * hred[c] - 1);
            const float v = Sl[c][tid];
            p += (cnt != 0.0f) ? v * v / cnt : 0.0f;
        }
        sred[tid] = p;
        __syncthreads();
        for (int k = 128; k; k >>= 1) {
            if (tid < k) sred[tid] += sred[tid + k];
            __syncthreads();
        }
        if (tid == 0) {
            float x = sred[0];
            for (int c = 0; c < 5; ++c) {
                const float Mc = (float)(ntps * hred[c]);
                const float cnt = Mc - 1.0f;
                x -= (cnt != 0.0f) ? Mc / cnt : 0.0f;
            }
            blocksum += INV_T * (x - (float)M);
        }
    }

    if (tid == 0) {
        atomicAdd(&acc_done[0], blocksum);
        __threadfence();
        int old = atomicAdd((int*)&acc_done[1], 1);
        if (old == nblk - 1) {
            float total = atomicAdd(&acc_done[0], 0.0f);  // atomic read
            out[0] = -total / (float)M;
        }
    }
}

extern "C" void kernel_launch(void* const* d_in, const int* in_sizes, int n_in,
                              void* d_out, int out_size, void* d_ws, size_t ws_size,
                              hipStream_t stream) {
    const float* features = (const float*)d_in[0];
    const int* labels_seg = (const int*)d_in[1];
    const int* labels_coords = (const int*)d_in[2];
    const int* crw = (const int*)d_in[3];
    const int* crh = (const int*)d_in[4];
    const int* crd = (const int*)d_in[5];
    float* out = (float*)d_out;

    const int N = in_sizes[2] / 3;          // 4096 patches
    const int M = in_sizes[0] / C_DIM;      // 8192 rows
    const int H = 128, W = 128, D = 128;
    const int nt = M / 128;                 // 64 row-blocks

    // workspace layout (no memsets needed — all exactly-once writes)
    char* ws = (char*)d_ws;
    unsigned char* g2 = (unsigned char*)ws;                  // 2 MB fp8 tiled
    char* p1 = ws + (size_t)M * C_DIM;
    int* lab = (int*)p1;                                     // N ints
    char* p2 = p1 + (size_t)N * 4;
    float* part = (float*)p2;                                // nt*M f32 (2 MB)
    char* p3 = p2 + (size_t)nt * M * 4;
    float* Spart = (float*)p3;                               // 128*5*256 f32 (640 KB)
    char* p4 = p3 + (size_t)128 * 1280 * 4;
    int* histpart = (int*)p4;                                // 128*8 ints
    float* acc_done = (float*)(p4 + 128 * 8 * 4);            // {acc, done}

    norm_kernel<<<M / 64, 256, 0, stream>>>(features, g2, labels_seg,
                                            labels_coords, crw, crh, crd, lab,
                                            Spart, histpart, acc_done,
                                            N, H, W, D);

    gram_kernel<<<512, 256, 0, stream>>>(g2, part, M, nt);

    const int fblk = M / 256;               // 32
    finalize_kernel<<<fblk, 256, 0, stream>>>(part, Spart, histpart, acc_done,
                                              out, M, N, nt, fblk);
}

// Round 13
// 126.127 us; speedup vs baseline: 1.2098x; 1.2013x over previous
//
#include <hip/hip_runtime.h>
#include <hip/hip_bf16.h>

typedef __attribute__((ext_vector_type(4))) float floatx4;

#define C_DIM 256
#define INV_T 14.285714285714286f
// (1/T) * log2(e) : logits scaled to base-2 so exp2f -> v_exp_f32 directly.
#define K2_SCALE 20.60992915f

// pack 4 fp32 -> 4 OCP fp8 e4m3 bytes in one dword (ascending order)
__device__ __forceinline__ unsigned int pack4fp8(float a, float b, float c, float d) {
    int w = __builtin_amdgcn_cvt_pk_fp8_f32(a, b, 0, false);
    w = __builtin_amdgcn_cvt_pk_fp8_f32(c, d, w, true);
    return (unsigned int)w;
}

// DPP add within a 16-lane row (VALU pipe; R10-proven)
template <int CTRL>
__device__ __forceinline__ float dppadd(float x) {
    int y = __builtin_amdgcn_update_dpp(0, __builtin_bit_cast(int, x),
                                        CTRL, 0xf, 0xf, true);
    return x + __builtin_bit_cast(float, y);
}
__device__ __forceinline__ float row16_sum(float x) {
    x = dppadd<0xB1>(x);    // quad_perm xor1
    x = dppadd<0x4E>(x);    // quad_perm xor2
    x = dppadd<0x124>(x);   // row_ror:4
    x = dppadd<0x128>(x);   // row_ror:8
    return x;
}

// ---------------------------------------------------------------------------
// Kernel 1: fused prep (no memsets — everything exactly-once). 128 blocks x
// 64 rows. Per 16-row group: labels from coords/seg, normalize 4 rows/wave
// -> LDS, fragment-tiled fp8 writer (16 B/thread), class-sum accumulation
// Sloc[5][256] (thread t owns dim t). End: slot writes Spart[bid][5][256],
// histpart[bid][8]; block 0 zeroes the finalize handshake.
// ---------------------------------------------------------------------------
__global__ __launch_bounds__(256) void
norm_kernel(const float* __restrict__ f,
            unsigned char* __restrict__ g2,
            const int* __restrict__ seg,
            const int* __restrict__ coords,
            const int* __restrict__ crw,
            const int* __restrict__ crh,
            const int* __restrict__ crd,
            int* __restrict__ lab,
            float* __restrict__ Spart,    // [128][5][256]
            int* __restrict__ histpart,   // [128][8]
            float* __restrict__ acc_done,
            int N, int H, int W, int D) {
    __shared__ float nrm[16][264];
    __shared__ float Sloc[5][256];
    __shared__ int lbl[16];
    __shared__ int histloc[8];

    const int tid = threadIdx.x;
    const int bid = blockIdx.x;
    const int lane = tid & 63;
    const int wave = tid >> 6;
    const int rbase = bid * 64;

    if (bid == 0 && tid == 0) {
        acc_done[0] = 0.0f;
        ((int*)acc_done)[1] = 0;
    }
    if (tid < 8) histloc[tid] = 0;
#pragma unroll
    for (int c = 0; c < 5; ++c) Sloc[c][tid] = 0.0f;
    __syncthreads();

    for (int g = 0; g < 4; ++g) {
        const int grow0 = rbase + g * 16;
        if (tid < 16) {
            const int row = grow0 + tid;
            const int p = row & (N - 1);
            int c0 = coords[3 * p + 0];
            int c1 = coords[3 * p + 1];
            int c2 = coords[3 * p + 2];
            int i0 = (c0 * H) / crw[0];
            int i1 = (c1 * W) / crh[0];
            int i2 = (c2 * D) / crd[0];
            const int c = seg[(i0 * W + i1) * D + i2];
            lbl[tid] = c;
            if (row < N) {
                lab[row] = c;
                atomicAdd(&histloc[c], 1);
            }
        }
        const int rl = wave * 4;
#pragma unroll
        for (int q = 0; q < 4; ++q) {
            const int row = grow0 + rl + q;
            const float4 v = ((const float4*)(f + (size_t)row * C_DIM))[lane];
            float ss = v.x * v.x + v.y * v.y + v.z * v.z + v.w * v.w;
#pragma unroll
            for (int off = 32; off; off >>= 1) ss += __shfl_xor(ss, off, 64);
            const float inv = 1.0f / sqrtf(ss);
            *(float4*)&nrm[rl + q][lane * 4] =
                float4{v.x * inv, v.y * inv, v.z * inv, v.w * inv};
        }
        __syncthreads();

        // fragment-tiled fp8 writer: thread t -> blob bytes [16t, 16t+16)
        const int k0 = (tid >> 5) * 32 + ((tid >> 3) & 3) * 8;
        const float* ra = &nrm[(2 * tid) & 15][k0];
        const float* rb = &nrm[(2 * tid + 1) & 15][k0];
        uint4 o;
        o.x = pack4fp8(ra[0], ra[1], ra[2], ra[3]);
        o.y = pack4fp8(ra[4], ra[5], ra[6], ra[7]);
        o.z = pack4fp8(rb[0], rb[1], rb[2], rb[3]);
        o.w = pack4fp8(rb[4], rb[5], rb[6], rb[7]);
        *(uint4*)(g2 + (size_t)(bid * 4 + g) * 4096 + (size_t)tid * 16) = o;

        // class-sum accumulation: thread t owns dim t
#pragma unroll
        for (int rr = 0; rr < 16; ++rr)
            Sloc[lbl[rr]][tid] += nrm[rr][tid];
        __syncthreads();
    }

#pragma unroll
    for (int c = 0; c < 5; ++c)
        Spart[(size_t)bid * 1280 + c * 256 + tid] = Sloc[c][tid];
    if (tid < 8) histpart[bid * 8 + tid] = histloc[tid];
}

// ---------------------------------------------------------------------------
// Kernel 2: chunked-persistent symmetric Gram kernel (se-only epilogue),
// unchanged from R11/R12 (verified absmax 0.0; ~37-43 us).
// ---------------------------------------------------------------------------
__global__ __launch_bounds__(256, 2) void
gram_kernel(const unsigned char* __restrict__ G2,
            float* __restrict__ part,
            int M, int nt) {
    __shared__ unsigned char Abuf[32768];
    __shared__ unsigned char Bbuf[32768];
    __shared__ float red[2][2][128];

    const int tid = threadIdx.x;
    const int bid = blockIdx.x;
    const int lane = tid & 63;
    const int wave = tid >> 6;
    const int waveM = wave >> 1;
    const int waveN = wave & 1;
    const int cc = lane & 15;
    const int cq = lane >> 4;

    const int start = bid * 4 + (bid < 32 ? bid : 32);
    const int len = 4 + (bid < 32 ? 1 : 0);
    int tmPrev = -1;

    for (int s = 0; s < len; ++s) {
        const int idx = start + s;
        float fnt = (float)nt;
        float disc = (2.0f * fnt + 1.0f) * (2.0f * fnt + 1.0f) - 8.0f * (float)idx;
        int tm = (int)((2.0f * fnt + 1.0f - sqrtf(disc)) * 0.5f);
        if (tm < 0) tm = 0;
        if (tm > nt - 1) tm = nt - 1;
        while (tm > 0 && idx < tm * nt - tm * (tm - 1) / 2) --tm;
        while (idx >= (tm + 1) * nt - (tm + 1) * tm / 2) ++tm;
        const int tn = tm + (idx - (tm * nt - tm * (tm - 1) / 2));

        const int rowA0 = tm * 128;
        const int rowB0 = tn * 128;
        const bool diagTile = (tm == tn);

        if (tm != tmPrev) {
            const unsigned char* gA = G2 + (size_t)tm * 32768;
#pragma unroll
            for (int i = 0; i < 8; ++i) {
                const int u = i * 256 + tid;
                __builtin_amdgcn_global_load_lds(
                    (const __attribute__((address_space(1))) void*)(gA + (size_t)u * 16),
                    (__attribute__((address_space(3))) void*)(&Abuf[(u & ~63) * 16]),
                    16, 0, 0);
            }
            tmPrev = tm;
        }
        if (!diagTile) {
            const unsigned char* gB = G2 + (size_t)tn * 32768;
#pragma unroll
            for (int i = 0; i < 8; ++i) {
                const int u = i * 256 + tid;
                __builtin_amdgcn_global_load_lds(
                    (const __attribute__((address_space(1))) void*)(gB + (size_t)u * 16),
                    (__attribute__((address_space(3))) void*)(&Bbuf[(u & ~63) * 16]),
                    16, 0, 0);
            }
        }
        __syncthreads();

        const unsigned char* A = Abuf;
        const unsigned char* B = diagTile ? Abuf : Bbuf;

        floatx4 acc[4][4];
#pragma unroll
        for (int mi = 0; mi < 4; ++mi)
#pragma unroll
            for (int ni = 0; ni < 4; ++ni)
                acc[mi][ni] = floatx4{-1.0f, -1.0f, -1.0f, -1.0f};  // folds (sim-1)

#pragma unroll
        for (int ks = 0; ks < 8; ++ks) {  // K = 8 * 32 = 256
            long af[4], bf[4];
#pragma unroll
            for (int mi = 0; mi < 4; ++mi)
                af[mi] = *(const long*)&A[(size_t)((waveM * 4 + mi) * 8 + ks) * 512 + lane * 8];
#pragma unroll
            for (int ni = 0; ni < 4; ++ni)
                bf[ni] = *(const long*)&B[(size_t)((waveN * 4 + ni) * 8 + ks) * 512 + lane * 8];
#pragma unroll
            for (int mi = 0; mi < 4; ++mi)
#pragma unroll
                for (int ni = 0; ni < 4; ++ni)
                    acc[mi][ni] = __builtin_amdgcn_mfma_f32_16x16x32_fp8_fp8(
                        af[mi], bf[ni], acc[mi][ni], 0, 0, 0);
        }

        // ---- se-only epilogue ----
        float bse[4] = {};
#pragma unroll
        for (int mi = 0; mi < 4; ++mi) {
#pragma unroll
            for (int r = 0; r < 4; ++r) {
                const int lrow = waveM * 64 + mi * 16 + cq * 4 + r;
                const int grow = rowA0 + lrow;
                float se = 0.0f;
#pragma unroll
                for (int ni = 0; ni < 4; ++ni) {
                    const int gcol = rowB0 + waveN * 64 + ni * 16 + cc;
                    const float e = exp2f(acc[mi][ni][r] * K2_SCALE);
                    const float ev = (gcol != grow) ? e : 0.0f;
                    se += ev;
                    bse[ni] += ev;
                }
                se = row16_sum(se);
                if (cc == 0) red[0][waveN][lrow] = se;
            }
        }
        if (!diagTile) {
#pragma unroll
            for (int ni = 0; ni < 4; ++ni) {
                float se = bse[ni];
                se += __shfl_xor(se, 16, 64);
                se += __shfl_xor(se, 32, 64);
                if (cq == 0) red[1][waveM][waveN * 64 + ni * 16 + cc] = se;
            }
        }
        __syncthreads();

        if (tid < 128)
            part[(size_t)tn * M + rowA0 + tid] = red[0][0][tid] + red[0][1][tid];
        if (!diagTile && tid >= 128)
            part[(size_t)tm * M + rowB0 + (tid - 128)] =
                red[1][0][tid - 128] + red[1][1][tid - 128];
        __syncthreads();
    }
}

// ---------------------------------------------------------------------------
// Kernel 3: finalize, fully parallel. Grid = fblk + 5 blocks.
//  Blocks 0..fblk-1 (32): per-row se = sum of 64 part slots (coalesced),
//    partial = -log(se), block tree-reduce, one atomicAdd.
//  Blocks fblk..fblk+4: class c = bid - fblk. Thread d sums Spart[b][c][d]
//    over the 128 norm-blocks with 8 independent accumulators (8+ loads in
//    flight -> latency-hidden), squares, tree-reduces to |S_c|^2; threads
//    0..127 reduce histpart for M_c. Contribution INV_T*((|S_c|^2-M_c)/cnt_c)
//    (+ block fblk adds -INV_T*M). Identity (R12-verified, absmax 0.0):
//    sum_i term_i = INV_T*(sum_c (|S_c|^2-M_c)/cnt_c - M) - sum_i log(se_i).
//  acc/done handshake over all fblk+5 blocks; last block writes the loss.
// ---------------------------------------------------------------------------
__global__ __launch_bounds__(256) void
finalize_kernel(const float* __restrict__ part,
                const float* __restrict__ Spart,
                const int* __restrict__ histpart,
                float* __restrict__ acc_done,
                float* __restrict__ out,
                int M, int N, int nslots, int fblk) {
    __shared__ float sred[256];
    __shared__ int hred[128];

    const int tid = threadIdx.x;
    const int bid = blockIdx.x;
    const int ntps = M / N;
    const int nblk = fblk + 5;
    float blocksum = 0.0f;

    if (bid < fblk) {
        // ---- per-row -log(sum exp) ----
        const int r0 = bid * 256;
        float se = 0.0f;
        for (int s = 0; s < nslots; ++s) se += part[(size_t)s * M + r0 + tid];
        sred[tid] = -logf(se);
        __syncthreads();
        for (int k = 128; k; k >>= 1) {
            if (tid < k) sred[tid] += sred[tid + k];
            __syncthreads();
        }
        blocksum = sred[0];
    } else {
        // ---- class-aggregate term, one class per block ----
        const int c = bid - fblk;
        float a0 = 0.0f, a1 = 0.0f, a2 = 0.0f, a3 = 0.0f;
        float a4 = 0.0f, a5 = 0.0f, a6 = 0.0f, a7 = 0.0f;
        const float* Sp = Spart + c * 256 + tid;
        for (int b = 0; b < 128; b += 8) {
            a0 += Sp[(size_t)(b + 0) * 1280];
            a1 += Sp[(size_t)(b + 1) * 1280];
            a2 += Sp[(size_t)(b + 2) * 1280];
            a3 += Sp[(size_t)(b + 3) * 1280];
            a4 += Sp[(size_t)(b + 4) * 1280];
            a5 += Sp[(size_t)(b + 5) * 1280];
            a6 += Sp[(size_t)(b + 6) * 1280];
            a7 += Sp[(size_t)(b + 7) * 1280];
        }
        const float v = ((a0 + a1) + (a2 + a3)) + ((a4 + a5) + (a6 + a7));
        sred[tid] = v * v;
        if (tid < 128) hred[tid] = histpart[tid * 8 + c];
        __syncthreads();
        for (int k = 128; k; k >>= 1) {
            if (tid < k) sred[tid] += sred[tid + k];
            if (tid < k / 2 && k >= 2) hred[tid] += hred[tid + k / 2];
            __syncthreads();
        }
        if (tid == 0) {
            const float S2 = sred[0];
            const float Mc = (float)(ntps * hred[0]);
            const float cnt = Mc - 1.0f;
            float contrib = (cnt > 0.0f) ? INV_T * (S2 - Mc) / cnt : 0.0f;
            if (c == 0) contrib -= INV_T * (float)M;
            blocksum = contrib;
        }
    }

    if (tid == 0) {
        atomicAdd(&acc_done[0], blocksum);
        __threadfence();
        int old = atomicAdd((int*)&acc_done[1], 1);
        if (old == nblk - 1) {
            float total = atomicAdd(&acc_done[0], 0.0f);  // atomic read
            out[0] = -total / (float)M;
        }
    }
}

extern "C" void kernel_launch(void* const* d_in, const int* in_sizes, int n_in,
                              void* d_out, int out_size, void* d_ws, size_t ws_size,
                              hipStream_t stream) {
    const float* features = (const float*)d_in[0];
    const int* labels_seg = (const int*)d_in[1];
    const int* labels_coords = (const int*)d_in[2];
    const int* crw = (const int*)d_in[3];
    const int* crh = (const int*)d_in[4];
    const int* crd = (const int*)d_in[5];
    float* out = (float*)d_out;

    const int N = in_sizes[2] / 3;          // 4096 patches
    const int M = in_sizes[0] / C_DIM;      // 8192 rows
    const int H = 128, W = 128, D = 128;
    const int nt = M / 128;                 // 64 row-blocks

    // workspace layout (no memsets — all exactly-once writes)
    char* ws = (char*)d_ws;
    unsigned char* g2 = (unsigned char*)ws;                  // 2 MB fp8 tiled
    char* p1 = ws + (size_t)M * C_DIM;
    int* lab = (int*)p1;                                     // N ints
    char* p2 = p1 + (size_t)N * 4;
    float* part = (float*)p2;                                // nt*M f32 (2 MB)
    char* p3 = p2 + (size_t)nt * M * 4;
    float* Spart = (float*)p3;                               // 128*5*256 f32 (640 KB)
    char* p4 = p3 + (size_t)128 * 1280 * 4;
    int* histpart = (int*)p4;                                // 128*8 ints
    float* acc_done = (float*)(p4 + 128 * 8 * 4);            // {acc, done}

    norm_kernel<<<M / 64, 256, 0, stream>>>(features, g2, labels_seg,
                                            labels_coords, crw, crh, crd, lab,
                                            Spart, histpart, acc_done,
                                            N, H, W, D);

    gram_kernel<<<512, 256, 0, stream>>>(g2, part, M, nt);

    const int fblk = M / 256;               // 32
    finalize_kernel<<<fblk + 5, 256, 0, stream>>>(part, Spart, histpart,
                                                  acc_done, out, M, N, nt, fblk);
}

// Round 14
// 122.558 us; speedup vs baseline: 1.2450x; 1.0291x over previous
//
#include <hip/hip_runtime.h>
#include <hip/hip_bf16.h>

typedef __attribute__((ext_vector_type(4))) float floatx4;

#define C_DIM 256
#define INV_T 14.285714285714286f
// (1/T) * log2(e) : logits scaled to base-2 so exp2f -> v_exp_f32 directly.
#define K2_SCALE 20.60992915f

// pack 4 fp32 -> 4 OCP fp8 e4m3 bytes in one dword (ascending order)
__device__ __forceinline__ unsigned int pack4fp8(float a, float b, float c, float d) {
    int w = __builtin_amdgcn_cvt_pk_fp8_f32(a, b, 0, false);
    w = __builtin_amdgcn_cvt_pk_fp8_f32(c, d, w, true);
    return (unsigned int)w;
}

// DPP add within a 16-lane row (VALU pipe; R10-proven)
template <int CTRL>
__device__ __forceinline__ float dppadd(float x) {
    int y = __builtin_amdgcn_update_dpp(0, __builtin_bit_cast(int, x),
                                        CTRL, 0xf, 0xf, true);
    return x + __builtin_bit_cast(float, y);
}
__device__ __forceinline__ float row16_sum(float x) {
    x = dppadd<0xB1>(x);    // quad_perm xor1
    x = dppadd<0x4E>(x);    // quad_perm xor2
    x = dppadd<0x124>(x);   // row_ror:4
    x = dppadd<0x128>(x);   // row_ror:8
    return x;
}

// ---------------------------------------------------------------------------
// Kernel 1: fused prep (no memsets — everything exactly-once). 256 blocks x
// 32 rows (2 groups of 16; halved serial group loop vs R13). Per group:
// labels from coords/seg, normalize 4 rows/wave -> LDS, fragment-tiled fp8
// writer (16 B/thread), class-sum accumulation Sloc[5][256] (thread t owns
// dim t). End: slot writes Spart[bid][5][256], histpart[bid][8]; block 0
// zeroes the finalize handshake.
// ---------------------------------------------------------------------------
__global__ __launch_bounds__(256) void
norm_kernel(const float* __restrict__ f,
            unsigned char* __restrict__ g2,
            const int* __restrict__ seg,
            const int* __restrict__ coords,
            const int* __restrict__ crw,
            const int* __restrict__ crh,
            const int* __restrict__ crd,
            int* __restrict__ lab,
            float* __restrict__ Spart,    // [256][5][256]
            int* __restrict__ histpart,   // [256][8]
            float* __restrict__ acc_done,
            int N, int H, int W, int D) {
    __shared__ float nrm[16][264];
    __shared__ float Sloc[5][256];
    __shared__ int lbl[16];
    __shared__ int histloc[8];

    const int tid = threadIdx.x;
    const int bid = blockIdx.x;
    const int lane = tid & 63;
    const int wave = tid >> 6;
    const int rbase = bid * 32;

    if (bid == 0 && tid == 0) {
        acc_done[0] = 0.0f;
        ((int*)acc_done)[1] = 0;
    }
    if (tid < 8) histloc[tid] = 0;
#pragma unroll
    for (int c = 0; c < 5; ++c) Sloc[c][tid] = 0.0f;
    __syncthreads();

    for (int g = 0; g < 2; ++g) {
        const int grow0 = rbase + g * 16;
        if (tid < 16) {
            const int row = grow0 + tid;
            const int p = row & (N - 1);
            int c0 = coords[3 * p + 0];
            int c1 = coords[3 * p + 1];
            int c2 = coords[3 * p + 2];
            int i0 = (c0 * H) / crw[0];
            int i1 = (c1 * W) / crh[0];
            int i2 = (c2 * D) / crd[0];
            const int c = seg[(i0 * W + i1) * D + i2];
            lbl[tid] = c;
            if (row < N) {
                lab[row] = c;
                atomicAdd(&histloc[c], 1);
            }
        }
        const int rl = wave * 4;
#pragma unroll
        for (int q = 0; q < 4; ++q) {
            const int row = grow0 + rl + q;
            const float4 v = ((const float4*)(f + (size_t)row * C_DIM))[lane];
            float ss = v.x * v.x + v.y * v.y + v.z * v.z + v.w * v.w;
#pragma unroll
            for (int off = 32; off; off >>= 1) ss += __shfl_xor(ss, off, 64);
            const float inv = 1.0f / sqrtf(ss);
            *(float4*)&nrm[rl + q][lane * 4] =
                float4{v.x * inv, v.y * inv, v.z * inv, v.w * inv};
        }
        __syncthreads();

        // fragment-tiled fp8 writer: thread t -> blob bytes [16t, 16t+16)
        const int k0 = (tid >> 5) * 32 + ((tid >> 3) & 3) * 8;
        const float* ra = &nrm[(2 * tid) & 15][k0];
        const float* rb = &nrm[(2 * tid + 1) & 15][k0];
        uint4 o;
        o.x = pack4fp8(ra[0], ra[1], ra[2], ra[3]);
        o.y = pack4fp8(ra[4], ra[5], ra[6], ra[7]);
        o.z = pack4fp8(rb[0], rb[1], rb[2], rb[3]);
        o.w = pack4fp8(rb[4], rb[5], rb[6], rb[7]);
        *(uint4*)(g2 + (size_t)(bid * 2 + g) * 4096 + (size_t)tid * 16) = o;

        // class-sum accumulation: thread t owns dim t
#pragma unroll
        for (int rr = 0; rr < 16; ++rr)
            Sloc[lbl[rr]][tid] += nrm[rr][tid];
        __syncthreads();
    }

#pragma unroll
    for (int c = 0; c < 5; ++c)
        Spart[(size_t)bid * 1280 + c * 256 + tid] = Sloc[c][tid];
    if (tid < 8) histpart[bid * 8 + tid] = histloc[tid];
}

// ---------------------------------------------------------------------------
// Kernel 2: chunked-persistent symmetric Gram kernel (se-only epilogue),
// R13 structure + wave-uniform diag/off-diag epilogue specialization:
// off-diag tiles (2016 of 2080) skip the diag compare/select entirely;
// diagonal tiles keep the mask but skip bse (mirror unused there).
// ---------------------------------------------------------------------------
__global__ __launch_bounds__(256, 2) void
gram_kernel(const unsigned char* __restrict__ G2,
            float* __restrict__ part,
            int M, int nt) {
    __shared__ unsigned char Abuf[32768];
    __shared__ unsigned char Bbuf[32768];
    __shared__ float red[2][2][128];

    const int tid = threadIdx.x;
    const int bid = blockIdx.x;
    const int lane = tid & 63;
    const int wave = tid >> 6;
    const int waveM = wave >> 1;
    const int waveN = wave & 1;
    const int cc = lane & 15;
    const int cq = lane >> 4;

    const int start = bid * 4 + (bid < 32 ? bid : 32);
    const int len = 4 + (bid < 32 ? 1 : 0);
    int tmPrev = -1;

    for (int s = 0; s < len; ++s) {
        const int idx = start + s;
        float fnt = (float)nt;
        float disc = (2.0f * fnt + 1.0f) * (2.0f * fnt + 1.0f) - 8.0f * (float)idx;
        int tm = (int)((2.0f * fnt + 1.0f - sqrtf(disc)) * 0.5f);
        if (tm < 0) tm = 0;
        if (tm > nt - 1) tm = nt - 1;
        while (tm > 0 && idx < tm * nt - tm * (tm - 1) / 2) --tm;
        while (idx >= (tm + 1) * nt - (tm + 1) * tm / 2) ++tm;
        const int tn = tm + (idx - (tm * nt - tm * (tm - 1) / 2));

        const int rowA0 = tm * 128;
        const int rowB0 = tn * 128;
        const bool diagTile = (tm == tn);

        if (tm != tmPrev) {
            const unsigned char* gA = G2 + (size_t)tm * 32768;
#pragma unroll
            for (int i = 0; i < 8; ++i) {
                const int u = i * 256 + tid;
                __builtin_amdgcn_global_load_lds(
                    (const __attribute__((address_space(1))) void*)(gA + (size_t)u * 16),
                    (__attribute__((address_space(3))) void*)(&Abuf[(u & ~63) * 16]),
                    16, 0, 0);
            }
            tmPrev = tm;
        }
        if (!diagTile) {
            const unsigned char* gB = G2 + (size_t)tn * 32768;
#pragma unroll
            for (int i = 0; i < 8; ++i) {
                const int u = i * 256 + tid;
                __builtin_amdgcn_global_load_lds(
                    (const __attribute__((address_space(1))) void*)(gB + (size_t)u * 16),
                    (__attribute__((address_space(3))) void*)(&Bbuf[(u & ~63) * 16]),
                    16, 0, 0);
            }
        }
        __syncthreads();

        const unsigned char* A = Abuf;
        const unsigned char* B = diagTile ? Abuf : Bbuf;

        floatx4 acc[4][4];
#pragma unroll
        for (int mi = 0; mi < 4; ++mi)
#pragma unroll
            for (int ni = 0; ni < 4; ++ni)
                acc[mi][ni] = floatx4{-1.0f, -1.0f, -1.0f, -1.0f};  // folds (sim-1)

#pragma unroll
        for (int ks = 0; ks < 8; ++ks) {  // K = 8 * 32 = 256
            long af[4], bf[4];
#pragma unroll
            for (int mi = 0; mi < 4; ++mi)
                af[mi] = *(const long*)&A[(size_t)((waveM * 4 + mi) * 8 + ks) * 512 + lane * 8];
#pragma unroll
            for (int ni = 0; ni < 4; ++ni)
                bf[ni] = *(const long*)&B[(size_t)((waveN * 4 + ni) * 8 + ks) * 512 + lane * 8];
#pragma unroll
            for (int mi = 0; mi < 4; ++mi)
#pragma unroll
                for (int ni = 0; ni < 4; ++ni)
                    acc[mi][ni] = __builtin_amdgcn_mfma_f32_16x16x32_fp8_fp8(
                        af[mi], bf[ni], acc[mi][ni], 0, 0, 0);
        }

        // ---- se-only epilogue, diag/off-diag specialized (wave-uniform) ----
        if (!diagTile) {
            float bse[4] = {};
#pragma unroll
            for (int mi = 0; mi < 4; ++mi) {
#pragma unroll
                for (int r = 0; r < 4; ++r) {
                    const int lrow = waveM * 64 + mi * 16 + cq * 4 + r;
                    float se = 0.0f;
#pragma unroll
                    for (int ni = 0; ni < 4; ++ni) {
                        const float e = exp2f(acc[mi][ni][r] * K2_SCALE);
                        se += e;
                        bse[ni] += e;
                    }
                    se = row16_sum(se);
                    if (cc == 0) red[0][waveN][lrow] = se;
                }
            }
#pragma unroll
            for (int ni = 0; ni < 4; ++ni) {
                float se = bse[ni];
                se += __shfl_xor(se, 16, 64);
                se += __shfl_xor(se, 32, 64);
                if (cq == 0) red[1][waveM][waveN * 64 + ni * 16 + cc] = se;
            }
        } else {
#pragma unroll
            for (int mi = 0; mi < 4; ++mi) {
#pragma unroll
                for (int r = 0; r < 4; ++r) {
                    const int lrow = waveM * 64 + mi * 16 + cq * 4 + r;
                    const int grow = rowA0 + lrow;
                    float se = 0.0f;
#pragma unroll
                    for (int ni = 0; ni < 4; ++ni) {
                        const int gcol = rowB0 + waveN * 64 + ni * 16 + cc;
                        const float e = exp2f(acc[mi][ni][r] * K2_SCALE);
                        se += (gcol != grow) ? e : 0.0f;
                    }
                    se = row16_sum(se);
                    if (cc == 0) red[0][waveN][lrow] = se;
                }
            }
        }
        __syncthreads();

        if (tid < 128)
            part[(size_t)tn * M + rowA0 + tid] = red[0][0][tid] + red[0][1][tid];
        if (!diagTile && tid >= 128)
            part[(size_t)tm * M + rowB0 + (tid - 128)] =
                red[1][0][tid - 128] + red[1][1][tid - 128];
        __syncthreads();
    }
}

// ---------------------------------------------------------------------------
// Kernel 3: finalize, fully parallel (R13-verified identity):
//   sum_i term_i = INV_T*(sum_c (|S_c|^2-M_c)/cnt_c - M) - sum_i log(se_i)
// Blocks 0..fblk-1: per-row se over 64 slots, -log, tree-reduce, atomic.
// Blocks fblk..fblk+4: one class each; 8-accumulator latency-hidden sweep
// over the 256 Spart slots, square, tree-reduce; hist reduce; contribution.
// acc/done handshake over fblk+5 blocks; last block writes the loss.
// ---------------------------------------------------------------------------
__global__ __launch_bounds__(256) void
finalize_kernel(const float* __restrict__ part,
                const float* __restrict__ Spart,
                const int* __restrict__ histpart,
                float* __restrict__ acc_done,
                float* __restrict__ out,
                int M, int N, int nslots, int fblk) {
    __shared__ float sred[256];
    __shared__ int hred[256];

    const int tid = threadIdx.x;
    const int bid = blockIdx.x;
    const int ntps = M / N;
    const int nblk = fblk + 5;
    float blocksum = 0.0f;

    if (bid < fblk) {
        const int r0 = bid * 256;
        float se = 0.0f;
        for (int s = 0; s < nslots; ++s) se += part[(size_t)s * M + r0 + tid];
        sred[tid] = -logf(se);
        __syncthreads();
        for (int k = 128; k; k >>= 1) {
            if (tid < k) sred[tid] += sred[tid + k];
            __syncthreads();
        }
        blocksum = sred[0];
    } else {
        const int c = bid - fblk;
        float a0 = 0.0f, a1 = 0.0f, a2 = 0.0f, a3 = 0.0f;
        float a4 = 0.0f, a5 = 0.0f, a6 = 0.0f, a7 = 0.0f;
        const float* Sp = Spart + c * 256 + tid;
        for (int b = 0; b < 256; b += 8) {
            a0 += Sp[(size_t)(b + 0) * 1280];
            a1 += Sp[(size_t)(b + 1) * 1280];
            a2 += Sp[(size_t)(b + 2) * 1280];
            a3 += Sp[(size_t)(b + 3) * 1280];
            a4 += Sp[(size_t)(b + 4) * 1280];
            a5 += Sp[(size_t)(b + 5) * 1280];
            a6 += Sp[(size_t)(b + 6) * 1280];
            a7 += Sp[(size_t)(b + 7) * 1280];
        }
        const float v = ((a0 + a1) + (a2 + a3)) + ((a4 + a5) + (a6 + a7));
        sred[tid] = v * v;
        hred[tid] = histpart[tid * 8 + c];
        __syncthreads();
        for (int k = 128; k; k >>= 1) {
            if (tid < k) {
                sred[tid] += sred[tid + k];
                hred[tid] += hred[tid + k];
            }
            __syncthreads();
        }
        if (tid == 0) {
            const float S2 = sred[0];
            const float Mc = (float)(ntps * hred[0]);
            const float cnt = Mc - 1.0f;
            float contrib = (cnt > 0.0f) ? INV_T * (S2 - Mc) / cnt : 0.0f;
            if (c == 0) contrib -= INV_T * (float)M;
            blocksum = contrib;
        }
    }

    if (tid == 0) {
        atomicAdd(&acc_done[0], blocksum);
        __threadfence();
        int old = atomicAdd((int*)&acc_done[1], 1);
        if (old == nblk - 1) {
            float total = atomicAdd(&acc_done[0], 0.0f);  // atomic read
            out[0] = -total / (float)M;
        }
    }
}

extern "C" void kernel_launch(void* const* d_in, const int* in_sizes, int n_in,
                              void* d_out, int out_size, void* d_ws, size_t ws_size,
                              hipStream_t stream) {
    const float* features = (const float*)d_in[0];
    const int* labels_seg = (const int*)d_in[1];
    const int* labels_coords = (const int*)d_in[2];
    const int* crw = (const int*)d_in[3];
    const int* crh = (const int*)d_in[4];
    const int* crd = (const int*)d_in[5];
    float* out = (float*)d_out;

    const int N = in_sizes[2] / 3;          // 4096 patches
    const int M = in_sizes[0] / C_DIM;      // 8192 rows
    const int H = 128, W = 128, D = 128;
    const int nt = M / 128;                 // 64 row-blocks

    // workspace layout (no memsets — all exactly-once writes)
    char* ws = (char*)d_ws;
    unsigned char* g2 = (unsigned char*)ws;                  // 2 MB fp8 tiled
    char* p1 = ws + (size_t)M * C_DIM;
    int* lab = (int*)p1;                                     // N ints
    char* p2 = p1 + (size_t)N * 4;
    float* part = (float*)p2;                                // nt*M f32 (2 MB)
    char* p3 = p2 + (size_t)nt * M * 4;
    float* Spart = (float*)p3;                               // 256*5*256 f32 (1.25 MB)
    char* p4 = p3 + (size_t)256 * 1280 * 4;
    int* histpart = (int*)p4;                                // 256*8 ints
    float* acc_done = (float*)(p4 + 256 * 8 * 4);            // {acc, done}

    norm_kernel<<<M / 32, 256, 0, stream>>>(features, g2, labels_seg,
                                            labels_coords, crw, crh, crd, lab,
                                            Spart, histpart, acc_done,
                                            N, H, W, D);

    gram_kernel<<<512, 256, 0, stream>>>(g2, part, M, nt);

    const int fblk = M / 256;               // 32
    finalize_kernel<<<fblk + 5, 256, 0, stream>>>(part, Spart, histpart,
                                                  acc_done, out, M, N, nt, fblk);
}

// Round 15
// 120.419 us; speedup vs baseline: 1.2671x; 1.0178x over previous
//
#include <hip/hip_runtime.h>
#include <hip/hip_bf16.h>

typedef __attribute__((ext_vector_type(4))) float floatx4;

#define C_DIM 256
#define INV_T 14.285714285714286f
// (1/T) * log2(e) : logits scaled to base-2 so exp2f -> v_exp_f32 directly.
#define K2_SCALE 20.60992915f

// pack 4 fp32 -> 4 OCP fp8 e4m3 bytes in one dword (ascending order)
__device__ __forceinline__ unsigned int pack4fp8(float a, float b, float c, float d) {
    int w = __builtin_amdgcn_cvt_pk_fp8_f32(a, b, 0, false);
    w = __builtin_amdgcn_cvt_pk_fp8_f32(c, d, w, true);
    return (unsigned int)w;
}

// DPP add within a 16-lane row (VALU pipe; R10-proven)
template <int CTRL>
__device__ __forceinline__ float dppadd(float x) {
    int y = __builtin_amdgcn_update_dpp(0, __builtin_bit_cast(int, x),
                                        CTRL, 0xf, 0xf, true);
    return x + __builtin_bit_cast(float, y);
}
__device__ __forceinline__ float row16_sum(float x) {
    x = dppadd<0xB1>(x);    // quad_perm xor1
    x = dppadd<0x4E>(x);    // quad_perm xor2
    x = dppadd<0x124>(x);   // row_ror:4
    x = dppadd<0x128>(x);   // row_ror:8
    return x;
}

// decode triangular tile index (wave-uniform; verified R5-R14)
__device__ __forceinline__ void decode_tile(int idx, int nt, int& tm, int& tn) {
    float fnt = (float)nt;
    float disc = (2.0f * fnt + 1.0f) * (2.0f * fnt + 1.0f) - 8.0f * (float)idx;
    int t = (int)((2.0f * fnt + 1.0f - sqrtf(disc)) * 0.5f);
    if (t < 0) t = 0;
    if (t > nt - 1) t = nt - 1;
    while (t > 0 && idx < t * nt - t * (t - 1) / 2) --t;
    while (idx >= (t + 1) * nt - (t + 1) * t / 2) ++t;
    tm = t;
    tn = t + (idx - (t * nt - t * (t - 1) / 2));
}

// ---------------------------------------------------------------------------
// Kernel 1: fused prep (no memsets — everything exactly-once). 256 blocks x
// 32 rows (2 groups of 16). Per group: labels from coords/seg, normalize
// 4 rows/wave -> LDS, fragment-tiled fp8 writer (16 B/thread), class-sum
// accumulation Sloc[5][256]. End: slot writes Spart[bid][5][256],
// histpart[bid][8]; block 0 zeroes the finalize handshake. (R14-verbatim)
// ---------------------------------------------------------------------------
__global__ __launch_bounds__(256) void
norm_kernel(const float* __restrict__ f,
            unsigned char* __restrict__ g2,
            const int* __restrict__ seg,
            const int* __restrict__ coords,
            const int* __restrict__ crw,
            const int* __restrict__ crh,
            const int* __restrict__ crd,
            int* __restrict__ lab,
            float* __restrict__ Spart,    // [256][5][256]
            int* __restrict__ histpart,   // [256][8]
            float* __restrict__ acc_done,
            int N, int H, int W, int D) {
    __shared__ float nrm[16][264];
    __shared__ float Sloc[5][256];
    __shared__ int lbl[16];
    __shared__ int histloc[8];

    const int tid = threadIdx.x;
    const int bid = blockIdx.x;
    const int lane = tid & 63;
    const int wave = tid >> 6;
    const int rbase = bid * 32;

    if (bid == 0 && tid == 0) {
        acc_done[0] = 0.0f;
        ((int*)acc_done)[1] = 0;
    }
    if (tid < 8) histloc[tid] = 0;
#pragma unroll
    for (int c = 0; c < 5; ++c) Sloc[c][tid] = 0.0f;
    __syncthreads();

    for (int g = 0; g < 2; ++g) {
        const int grow0 = rbase + g * 16;
        if (tid < 16) {
            const int row = grow0 + tid;
            const int p = row & (N - 1);
            int c0 = coords[3 * p + 0];
            int c1 = coords[3 * p + 1];
            int c2 = coords[3 * p + 2];
            int i0 = (c0 * H) / crw[0];
            int i1 = (c1 * W) / crh[0];
            int i2 = (c2 * D) / crd[0];
            const int c = seg[(i0 * W + i1) * D + i2];
            lbl[tid] = c;
            if (row < N) {
                lab[row] = c;
                atomicAdd(&histloc[c], 1);
            }
        }
        const int rl = wave * 4;
#pragma unroll
        for (int q = 0; q < 4; ++q) {
            const int row = grow0 + rl + q;
            const float4 v = ((const float4*)(f + (size_t)row * C_DIM))[lane];
            float ss = v.x * v.x + v.y * v.y + v.z * v.z + v.w * v.w;
#pragma unroll
            for (int off = 32; off; off >>= 1) ss += __shfl_xor(ss, off, 64);
            const float inv = 1.0f / sqrtf(ss);
            *(float4*)&nrm[rl + q][lane * 4] =
                float4{v.x * inv, v.y * inv, v.z * inv, v.w * inv};
        }
        __syncthreads();

        // fragment-tiled fp8 writer: thread t -> blob bytes [16t, 16t+16)
        const int k0 = (tid >> 5) * 32 + ((tid >> 3) & 3) * 8;
        const float* ra = &nrm[(2 * tid) & 15][k0];
        const float* rb = &nrm[(2 * tid + 1) & 15][k0];
        uint4 o;
        o.x = pack4fp8(ra[0], ra[1], ra[2], ra[3]);
        o.y = pack4fp8(ra[4], ra[5], ra[6], ra[7]);
        o.z = pack4fp8(rb[0], rb[1], rb[2], rb[3]);
        o.w = pack4fp8(rb[4], rb[5], rb[6], rb[7]);
        *(uint4*)(g2 + (size_t)(bid * 2 + g) * 4096 + (size_t)tid * 16) = o;

        // class-sum accumulation: thread t owns dim t
#pragma unroll
        for (int rr = 0; rr < 16; ++rr)
            Sloc[lbl[rr]][tid] += nrm[rr][tid];
        __syncthreads();
    }

#pragma unroll
    for (int c = 0; c < 5; ++c)
        Spart[(size_t)bid * 1280 + c * 256 + tid] = Sloc[c][tid];
    if (tid < 8) histpart[bid * 8 + tid] = histloc[tid];
}

// ---------------------------------------------------------------------------
// Kernel 2: chunked-persistent symmetric Gram kernel, PREFETCH-OVERLAPPED
// staging. Per tile: top __syncthreads (drains vmcnt -> DMA complete),
// K-loop (MFMA from LDS), __syncthreads (A/B no longer read), then ISSUE
// the NEXT tile's panel DMA (A only on tm change; B only if next off-diag)
// so the 32 KB DMA overlaps the current epilogue's VALU + stores. Epilogue
// reads only acc regs + red[] (never A/B) -> overlap is race-free.
// Se-only, diag/off-diag specialized (R14-verified).
// ---------------------------------------------------------------------------
__global__ __launch_bounds__(256, 2) void
gram_kernel(const unsigned char* __restrict__ G2,
            float* __restrict__ part,
            int M, int nt) {
    __shared__ unsigned char Abuf[32768];
    __shared__ unsigned char Bbuf[32768];
    __shared__ float red[2][2][128];

    const int tid = threadIdx.x;
    const int bid = blockIdx.x;
    const int lane = tid & 63;
    const int wave = tid >> 6;
    const int waveM = wave >> 1;
    const int waveN = wave & 1;
    const int cc = lane & 15;
    const int cq = lane >> 4;

    const int start = bid * 4 + (bid < 32 ? bid : 32);
    const int len = 4 + (bid < 32 ? 1 : 0);

    int tmCur, tnCur;
    decode_tile(start, nt, tmCur, tnCur);

    // prologue: stage first tile's panels
    {
        const unsigned char* gA = G2 + (size_t)tmCur * 32768;
#pragma unroll
        for (int i = 0; i < 8; ++i) {
            const int u = i * 256 + tid;
            __builtin_amdgcn_global_load_lds(
                (const __attribute__((address_space(1))) void*)(gA + (size_t)u * 16),
                (__attribute__((address_space(3))) void*)(&Abuf[(u & ~63) * 16]),
                16, 0, 0);
        }
        if (tnCur != tmCur) {
            const unsigned char* gB = G2 + (size_t)tnCur * 32768;
#pragma unroll
            for (int i = 0; i < 8; ++i) {
                const int u = i * 256 + tid;
                __builtin_amdgcn_global_load_lds(
                    (const __attribute__((address_space(1))) void*)(gB + (size_t)u * 16),
                    (__attribute__((address_space(3))) void*)(&Bbuf[(u & ~63) * 16]),
                    16, 0, 0);
            }
        }
    }

    for (int s = 0; s < len; ++s) {
        const int tm = tmCur, tn = tnCur;
        const int rowA0 = tm * 128;
        const int rowB0 = tn * 128;
        const bool diagTile = (tm == tn);
        const unsigned char* A = Abuf;
        const unsigned char* B = diagTile ? Abuf : Bbuf;

        __syncthreads();   // DMA complete (vmcnt drained) + red[] reads done

        floatx4 acc[4][4];
#pragma unroll
        for (int mi = 0; mi < 4; ++mi)
#pragma unroll
            for (int ni = 0; ni < 4; ++ni)
                acc[mi][ni] = floatx4{-1.0f, -1.0f, -1.0f, -1.0f};  // folds (sim-1)

#pragma unroll
        for (int ks = 0; ks < 8; ++ks) {  // K = 8 * 32 = 256
            long af[4], bf[4];
#pragma unroll
            for (int mi = 0; mi < 4; ++mi)
                af[mi] = *(const long*)&A[(size_t)((waveM * 4 + mi) * 8 + ks) * 512 + lane * 8];
#pragma unroll
            for (int ni = 0; ni < 4; ++ni)
                bf[ni] = *(const long*)&B[(size_t)((waveN * 4 + ni) * 8 + ks) * 512 + lane * 8];
#pragma unroll
            for (int mi = 0; mi < 4; ++mi)
#pragma unroll
                for (int ni = 0; ni < 4; ++ni)
                    acc[mi][ni] = __builtin_amdgcn_mfma_f32_16x16x32_fp8_fp8(
                        af[mi], bf[ni], acc[mi][ni], 0, 0, 0);
        }

        __syncthreads();   // all waves done reading A/B -> safe to overwrite

        // ---- prefetch next tile's panels (overlaps epilogue below) ----
        if (s + 1 < len) {
            int tmN, tnN;
            decode_tile(start + s + 1, nt, tmN, tnN);
            if (tmN != tm) {
                const unsigned char* gA = G2 + (size_t)tmN * 32768;
#pragma unroll
                for (int i = 0; i < 8; ++i) {
                    const int u = i * 256 + tid;
                    __builtin_amdgcn_global_load_lds(
                        (const __attribute__((address_space(1))) void*)(gA + (size_t)u * 16),
                        (__attribute__((address_space(3))) void*)(&Abuf[(u & ~63) * 16]),
                        16, 0, 0);
                }
            }
            if (tnN != tmN) {
                const unsigned char* gB = G2 + (size_t)tnN * 32768;
#pragma unroll
                for (int i = 0; i < 8; ++i) {
                    const int u = i * 256 + tid;
                    __builtin_amdgcn_global_load_lds(
                        (const __attribute__((address_space(1))) void*)(gB + (size_t)u * 16),
                        (__attribute__((address_space(3))) void*)(&Bbuf[(u & ~63) * 16]),
                        16, 0, 0);
                }
            }
            tmCur = tmN;
            tnCur = tnN;
        }

        // ---- se-only epilogue (acc regs + red[] only), diag-specialized ----
        if (!diagTile) {
            float bse[4] = {};
#pragma unroll
            for (int mi = 0; mi < 4; ++mi) {
#pragma unroll
                for (int r = 0; r < 4; ++r) {
                    const int lrow = waveM * 64 + mi * 16 + cq * 4 + r;
                    float se = 0.0f;
#pragma unroll
                    for (int ni = 0; ni < 4; ++ni) {
                        const float e = exp2f(acc[mi][ni][r] * K2_SCALE);
                        se += e;
                        bse[ni] += e;
                    }
                    se = row16_sum(se);
                    if (cc == 0) red[0][waveN][lrow] = se;
                }
            }
#pragma unroll
            for (int ni = 0; ni < 4; ++ni) {
                float se = bse[ni];
                se += __shfl_xor(se, 16, 64);
                se += __shfl_xor(se, 32, 64);
                if (cq == 0) red[1][waveM][waveN * 64 + ni * 16 + cc] = se;
            }
        } else {
#pragma unroll
            for (int mi = 0; mi < 4; ++mi) {
#pragma unroll
                for (int r = 0; r < 4; ++r) {
                    const int lrow = waveM * 64 + mi * 16 + cq * 4 + r;
                    const int grow = rowA0 + lrow;
                    float se = 0.0f;
#pragma unroll
                    for (int ni = 0; ni < 4; ++ni) {
                        const int gcol = rowB0 + waveN * 64 + ni * 16 + cc;
                        const float e = exp2f(acc[mi][ni][r] * K2_SCALE);
                        se += (gcol != grow) ? e : 0.0f;
                    }
                    se = row16_sum(se);
                    if (cc == 0) red[0][waveN][lrow] = se;
                }
            }
        }
        __syncthreads();   // red[] writes visible

        if (tid < 128)
            part[(size_t)tn * M + rowA0 + tid] = red[0][0][tid] + red[0][1][tid];
        if (!diagTile && tid >= 128)
            part[(size_t)tm * M + rowB0 + (tid - 128)] =
                red[1][0][tid - 128] + red[1][1][tid - 128];
        // no trailing barrier: the top-of-loop sync covers red[] reuse
    }
}

// ---------------------------------------------------------------------------
// Kernel 3: finalize, fully parallel (R13/R14-verified identity):
//   sum_i term_i = INV_T*(sum_c (|S_c|^2-M_c)/cnt_c - M) - sum_i log(se_i)
// Blocks 0..fblk-1: per-row se over 64 slots, -log, tree-reduce, atomic.
// Blocks fblk..fblk+4: one class each; 8-accumulator latency-hidden sweep
// over the 256 Spart slots, square, tree-reduce; hist reduce; contribution.
// acc/done handshake over fblk+5 blocks; last block writes the loss.
// ---------------------------------------------------------------------------
__global__ __launch_bounds__(256) void
finalize_kernel(const float* __restrict__ part,
                const float* __restrict__ Spart,
                const int* __restrict__ histpart,
                float* __restrict__ acc_done,
                float* __restrict__ out,
                int M, int N, int nslots, int fblk) {
    __shared__ float sred[256];
    __shared__ int hred[256];

    const int tid = threadIdx.x;
    const int bid = blockIdx.x;
    const int ntps = M / N;
    const int nblk = fblk + 5;
    float blocksum = 0.0f;

    if (bid < fblk) {
        const int r0 = bid * 256;
        float se = 0.0f;
        for (int s = 0; s < nslots; ++s) se += part[(size_t)s * M + r0 + tid];
        sred[tid] = -logf(se);
        __syncthreads();
        for (int k = 128; k; k >>= 1) {
            if (tid < k) sred[tid] += sred[tid + k];
            __syncthreads();
        }
        blocksum = sred[0];
    } else {
        const int c = bid - fblk;
        float a0 = 0.0f, a1 = 0.0f, a2 = 0.0f, a3 = 0.0f;
        float a4 = 0.0f, a5 = 0.0f, a6 = 0.0f, a7 = 0.0f;
        const float* Sp = Spart + c * 256 + tid;
        for (int b = 0; b < 256; b += 8) {
            a0 += Sp[(size_t)(b + 0) * 1280];
            a1 += Sp[(size_t)(b + 1) * 1280];
            a2 += Sp[(size_t)(b + 2) * 1280];
            a3 += Sp[(size_t)(b + 3) * 1280];
            a4 += Sp[(size_t)(b + 4) * 1280];
            a5 += Sp[(size_t)(b + 5) * 1280];
            a6 += Sp[(size_t)(b + 6) * 1280];
            a7 += Sp[(size_t)(b + 7) * 1280];
        }
        const float v = ((a0 + a1) + (a2 + a3)) + ((a4 + a5) + (a6 + a7));
        sred[tid] = v * v;
        hred[tid] = histpart[tid * 8 + c];
        __syncthreads();
        for (int k = 128; k; k >>= 1) {
            if (tid < k) {
                sred[tid] += sred[tid + k];
                hred[tid] += hred[tid + k];
            }
            __syncthreads();
        }
        if (tid == 0) {
            const float S2 = sred[0];
            const float Mc = (float)(ntps * hred[0]);
            const float cnt = Mc - 1.0f;
            float contrib = (cnt > 0.0f) ? INV_T * (S2 - Mc) / cnt : 0.0f;
            if (c == 0) contrib -= INV_T * (float)M;
            blocksum = contrib;
        }
    }

    if (tid == 0) {
        atomicAdd(&acc_done[0], blocksum);
        __threadfence();
        int old = atomicAdd((int*)&acc_done[1], 1);
        if (old == nblk - 1) {
            float total = atomicAdd(&acc_done[0], 0.0f);  // atomic read
            out[0] = -total / (float)M;
        }
    }
}

extern "C" void kernel_launch(void* const* d_in, const int* in_sizes, int n_in,
                              void* d_out, int out_size, void* d_ws, size_t ws_size,
                              hipStream_t stream) {
    const float* features = (const float*)d_in[0];
    const int* labels_seg = (const int*)d_in[1];
    const int* labels_coords = (const int*)d_in[2];
    const int* crw = (const int*)d_in[3];
    const int* crh = (const int*)d_in[4];
    const int* crd = (const int*)d_in[5];
    float* out = (float*)d_out;

    const int N = in_sizes[2] / 3;          // 4096 patches
    const int M = in_sizes[0] / C_DIM;      // 8192 rows
    const int H = 128, W = 128, D = 128;
    const int nt = M / 128;                 // 64 row-blocks

    // workspace layout (no memsets — all exactly-once writes)
    char* ws = (char*)d_ws;
    unsigned char* g2 = (unsigned char*)ws;                  // 2 MB fp8 tiled
    char* p1 = ws + (size_t)M * C_DIM;
    int* lab = (int*)p1;                                     // N ints
    char* p2 = p1 + (size_t)N * 4;
    float* part = (float*)p2;                                // nt*M f32 (2 MB)
    char* p3 = p2 + (size_t)nt * M * 4;
    float* Spart = (float*)p3;                               // 256*5*256 f32 (1.25 MB)
    char* p4 = p3 + (size_t)256 * 1280 * 4;
    int* histpart = (int*)p4;                                // 256*8 ints
    float* acc_done = (float*)(p4 + 256 * 8 * 4);            // {acc, done}

    norm_kernel<<<M / 32, 256, 0, stream>>>(features, g2, labels_seg,
                                            labels_coords, crw, crh, crd, lab,
                                            Spart, histpart, acc_done,
                                            N, H, W, D);

    gram_kernel<<<512, 256, 0, stream>>>(g2, part, M, nt);

    const int fblk = M / 256;               // 32
    finalize_kernel<<<fblk + 5, 256, 0, stream>>>(part, Spart, histpart,
                                                  acc_done, out, M, N, nt, fblk);
}